// Round 1
// baseline (226.383 us; speedup 1.0000x reference)
//
#include <hip/hip_runtime.h>
#include <stdint.h>

typedef uint16_t u16;
typedef uint32_t u32;
typedef __attribute__((ext_vector_type(8))) _Float16 f16x8;
typedef __attribute__((ext_vector_type(4))) float f32x4;

#define NB 2
#define NT 2048
#define NC 1024
#define NH 16
#define ND 64
#define NM (NB*NT)   // 4096 rows of x

__device__ __forceinline__ u16 f2h(float f) {
  _Float16 h = (_Float16)f;   // RNE
  return __builtin_bit_cast(u16, h);
}

// ---------------- f32 -> f16 convert, 4 elems/thread ----------------
__global__ __launch_bounds__(256) void cvt_kernel(const float* __restrict__ src,
                                                  u16* __restrict__ dst, int n4) {
  int i = blockIdx.x * 256 + threadIdx.x;
  if (i >= n4) return;
  float4 v = ((const float4*)src)[i];
  ushort4 o;
  o.x = f2h(v.x); o.y = f2h(v.y); o.z = f2h(v.z); o.w = f2h(v.w);
  ((ushort4*)dst)[i] = o;
}

// ---------------- async global->LDS 16B ----------------
__device__ __forceinline__ void gload16(const void* g, void* l) {
  __builtin_amdgcn_global_load_lds(
      (const __attribute__((address_space(1))) void*)g,
      (__attribute__((address_space(3))) void*)l, 16, 0, 0);
}

// ---------------- GEMM, both operands k-major (C[m][n] = sum_k A[m][k]*B[n][k]) ---
// EPI 0: QKV epilogue (scatter q/k [BH][T][D] f16, v transposed [BH][D][T] f16, q*=0.125)
// EPI 1: f32 row-major output
template<int EPI>
__global__ __launch_bounds__(256) void gemm_bt(const u16* __restrict__ A,
                                               const u16* __restrict__ Bw,
                                               int K, int N,
                                               u16* __restrict__ oq, u16* __restrict__ okk,
                                               u16* __restrict__ ovt,
                                               float* __restrict__ of) {
  __shared__ __align__(16) u16 Al[128*64];
  __shared__ __align__(16) u16 Bl[128*64];
  const int tid = threadIdx.x, lane = tid & 63, wid = tid >> 6;
  const int wm = wid >> 1, wn = wid & 1;
  const int m0 = blockIdx.y * 128, n0 = blockIdx.x * 128;
  const int srow = lane >> 3;          // row within an 8-row staging issue
  const int scol = (lane & 7) * 8;     // k-offset (elements) within row

  f32x4 acc[4][4] = {};

  for (int kt = 0; kt < K; kt += 64) {
    // stage A[128][64], B[128][64] linear; wave w covers rows [w*32, w*32+32)
    #pragma unroll
    for (int pp = 0; pp < 4; ++pp) {
      int r = wid*32 + pp*8;
      gload16(A  + (size_t)(m0 + r + srow)*K + kt + scol, &Al[r*64]);
      gload16(Bw + (size_t)(n0 + r + srow)*K + kt + scol, &Bl[r*64]);
    }
    __syncthreads();   // drains vmcnt -> LDS tiles ready
    #pragma unroll
    for (int kk = 0; kk < 2; ++kk) {
      f16x8 af[4], bfr[4];
      #pragma unroll
      for (int mt = 0; mt < 4; ++mt)
        af[mt] = *(const f16x8*)&Al[(wm*64 + mt*16 + (lane&15))*64 + kk*32 + 8*(lane>>4)];
      #pragma unroll
      for (int nt = 0; nt < 4; ++nt)
        bfr[nt] = *(const f16x8*)&Bl[(wn*64 + nt*16 + (lane&15))*64 + kk*32 + 8*(lane>>4)];
      #pragma unroll
      for (int mt = 0; mt < 4; ++mt)
        #pragma unroll
        for (int nt = 0; nt < 4; ++nt)
          acc[mt][nt] = __builtin_amdgcn_mfma_f32_16x16x32_f16(af[mt], bfr[nt], acc[mt][nt], 0, 0, 0);
    }
    __syncthreads();   // all reads done before next overwrite
  }

  if (EPI == 0) {
    #pragma unroll
    for (int nt = 0; nt < 4; ++nt) {
      int n = n0 + wn*64 + nt*16 + (lane & 15);
      int sel = n >> 10;          // 0=q, 1=k, 2=v
      int nn = n & 1023;
      int h = nn >> 6, d = nn & 63;
      float scale = (sel == 0) ? 0.125f : 1.0f;
      #pragma unroll
      for (int mt = 0; mt < 4; ++mt) {
        #pragma unroll
        for (int r = 0; r < 4; ++r) {
          int m = m0 + wm*64 + mt*16 + (lane>>4)*4 + r;   // D-layout row
          int b = m >> 11, t = m & (NT-1);
          u16 val = f2h(acc[mt][nt][r] * scale);
          int bh = b*NH + h;
          if (sel == 0)      oq [((size_t)bh*NT + t)*ND + d] = val;
          else if (sel == 1) okk[((size_t)bh*NT + t)*ND + d] = val;
          else               ovt[((size_t)bh*ND + d)*NT + t] = val;
        }
      }
    }
  } else {
    #pragma unroll
    for (int mt = 0; mt < 4; ++mt)
      #pragma unroll
      for (int r = 0; r < 4; ++r) {
        int m = m0 + wm*64 + mt*16 + (lane>>4)*4 + r;
        #pragma unroll
        for (int nt = 0; nt < 4; ++nt) {
          int n = n0 + wn*64 + nt*16 + (lane & 15);
          of[(size_t)m*N + n] = acc[mt][nt][r];
        }
      }
  }
}

// ---------------- flash attention, causal ----------------
// grid: x = T/64 q-tiles, y = B*H. 4 waves x 16 q-rows. KV tile = 64.
// q pre-scaled by 1/sqrt(D). k: [BH][T][D], vt: [BH][D][T] (transposed).
// LDS tiles XOR-swizzled: uhalf-col ^= (row&7)<<3  (16B-slot granularity).
__global__ __launch_bounds__(256) void attn_kernel(const u16* __restrict__ q,
                                                   const u16* __restrict__ k,
                                                   const u16* __restrict__ vt,
                                                   u16* __restrict__ y) {
  __shared__ __align__(16) u16 Kl[64*64];
  __shared__ __align__(16) u16 Vl[64*64];
  __shared__ __align__(16) u16 Pl[4*16*64];
  const int tid = threadIdx.x, lane = tid & 63, wid = tid >> 6;
  const int bh = blockIdx.y;
  const int qs = blockIdx.x * 64;
  const u16* qp = q  + (size_t)bh*NT*ND;
  const u16* kp = k  + (size_t)bh*NT*ND;
  const u16* vp = vt + (size_t)bh*ND*NT;

  // Q A-fragments held in registers for the whole kernel (rows qs+wid*16+(lane&15))
  f16x8 aq[2];
  {
    int t = qs + wid*16 + (lane & 15);
    #pragma unroll
    for (int c = 0; c < 2; ++c)
      aq[c] = *(const f16x8*)(qp + (size_t)t*ND + c*32 + 8*(lane>>4));
  }

  f32x4 accO[4] = {};
  float m_run[4], ssum[4];
  #pragma unroll
  for (int r = 0; r < 4; ++r) { m_run[r] = -1e30f; ssum[r] = 0.f; }

  const int srow = lane >> 3;
  const int scol8 = (lane & 7) ^ (srow & 7);   // pre-swizzled 16B-slot in global source

  const int ntiles = qs/64 + 1;                // causal: kv tiles 0..qs/64
  for (int kt = 0; kt < ntiles; ++kt) {
    const int kvs = kt * 64;
    // stage K[64][64] and Vt[64][64]; 8 issues each (8 rows / issue), wave w: 2w, 2w+1
    #pragma unroll
    for (int pp = 0; pp < 2; ++pp) {
      int issue = wid*2 + pp;
      int row = issue*8 + srow;
      gload16(kp + (size_t)(kvs + row)*ND + scol8*8, &Kl[issue*512]);
      gload16(vp + (size_t)row*NT + kvs + scol8*8, &Vl[issue*512]);
    }
    __syncthreads();

    // S = Q K^T (scale folded into q)
    f32x4 sacc[4] = {};
    #pragma unroll
    for (int c = 0; c < 2; ++c) {
      #pragma unroll
      for (int nt = 0; nt < 4; ++nt) {
        int row = nt*16 + (lane & 15);
        int col = (c*32 + 8*(lane>>4)) ^ ((row & 7) << 3);
        f16x8 kb = *(const f16x8*)&Kl[row*64 + col];
        sacc[nt] = __builtin_amdgcn_mfma_f32_16x16x32_f16(aq[c], kb, sacc[nt], 0, 0, 0);
      }
    }

    // causal mask + online softmax (rows live in 16-lane groups; 4 rows/lane-group)
    const int qrow_base = qs + wid*16 + (lane>>4)*4;
    float pv[4][4]; // [nt][r]
    #pragma unroll
    for (int r = 0; r < 4; ++r) {
      int qg = qrow_base + r;
      float s0[4];
      #pragma unroll
      for (int nt = 0; nt < 4; ++nt) {
        int kvg = kvs + nt*16 + (lane & 15);
        s0[nt] = (kvg > qg) ? -1e30f : sacc[nt][r];
      }
      float mloc = fmaxf(fmaxf(s0[0], s0[1]), fmaxf(s0[2], s0[3]));
      #pragma unroll
      for (int off = 1; off < 16; off <<= 1)
        mloc = fmaxf(mloc, __shfl_xor(mloc, off));
      float mnew = fmaxf(m_run[r], mloc);
      float alpha = __expf(m_run[r] - mnew);
      float ps = 0.f;
      #pragma unroll
      for (int nt = 0; nt < 4; ++nt) { float e = __expf(s0[nt] - mnew); pv[nt][r] = e; ps += e; }
      #pragma unroll
      for (int off = 1; off < 16; off <<= 1)
        ps += __shfl_xor(ps, off);
      ssum[r] = ssum[r]*alpha + ps;
      m_run[r] = mnew;
      #pragma unroll
      for (int nt = 0; nt < 4; ++nt) accO[nt][r] *= alpha;
    }

    // P -> LDS (f16, swizzled), per-wave private region
    u16* pl = &Pl[wid*1024];
    #pragma unroll
    for (int r = 0; r < 4; ++r) {
      int row = (lane>>4)*4 + r;
      #pragma unroll
      for (int nt = 0; nt < 4; ++nt) {
        int col = (nt*16 + (lane & 15)) ^ ((row & 7) << 3);
        pl[row*64 + col] = f2h(pv[nt][r]);
      }
    }

    // O += P V
    #pragma unroll
    for (int c = 0; c < 2; ++c) {
      int prow = lane & 15;
      int pcol = (c*32 + 8*(lane>>4)) ^ ((prow & 7) << 3);
      f16x8 pa = *(const f16x8*)&pl[prow*64 + pcol];
      #pragma unroll
      for (int nt = 0; nt < 4; ++nt) {
        int vrow = nt*16 + (lane & 15);
        int vcol = (c*32 + 8*(lane>>4)) ^ ((vrow & 7) << 3);
        f16x8 vb = *(const f16x8*)&Vl[vrow*64 + vcol];
        accO[nt] = __builtin_amdgcn_mfma_f32_16x16x32_f16(pa, vb, accO[nt], 0, 0, 0);
      }
    }
    __syncthreads();   // PV reads done before next tile staging
  }

  // epilogue: y[b][t][h*64+d] = O / ssum, f16
  const int b = bh >> 4, h = bh & 15;
  #pragma unroll
  for (int r = 0; r < 4; ++r) {
    int t = qs + wid*16 + (lane>>4)*4 + r;
    float inv = 1.0f / ssum[r];
    #pragma unroll
    for (int nt = 0; nt < 4; ++nt) {
      int d = nt*16 + (lane & 15);
      y[((size_t)(b*NT + t))*NC + h*ND + d] = f2h(accO[nt][r] * inv);
    }
  }
}

// ---------------- launch ----------------
extern "C" void kernel_launch(void* const* d_in, const int* in_sizes, int n_in,
                              void* d_out, int out_size, void* d_ws, size_t ws_size,
                              hipStream_t stream) {
  const float* x  = (const float*)d_in[0];
  const float* Wq = (const float*)d_in[1];
  const float* Wk = (const float*)d_in[2];
  const float* Wv = (const float*)d_in[3];
  const float* Wp = (const float*)d_in[4];

  u16* xb   = (u16*)d_ws;                       // [4096][1024]
  u16* wqkv = xb   + (size_t)NM*NC;             // [3072][1024] (Wq|Wk|Wv rows)
  u16* wpj  = wqkv + (size_t)3*NC*NC;           // [1024][1024]
  u16* qb   = wpj  + (size_t)NC*NC;             // [BH][T][D], pre-scaled 1/8
  u16* kb   = qb   + (size_t)NM*NC;             // [BH][T][D]
  u16* vtb  = kb   + (size_t)NM*NC;             // [BH][D][T]
  u16* yb   = vtb  + (size_t)NM*NC;             // [4096][1024]
  size_t need = ((size_t)NM*NC*5 + (size_t)4*NC*NC) * sizeof(u16);
  if (ws_size < need) return;                   // fail loudly (output stays zero)

  cvt_kernel<<<NM*NC/4/256, 256, 0, stream>>>(x,  xb,             NM*NC/4);
  cvt_kernel<<<NC*NC/4/256, 256, 0, stream>>>(Wq, wqkv,           NC*NC/4);
  cvt_kernel<<<NC*NC/4/256, 256, 0, stream>>>(Wk, wqkv + NC*NC,   NC*NC/4);
  cvt_kernel<<<NC*NC/4/256, 256, 0, stream>>>(Wv, wqkv + 2*NC*NC, NC*NC/4);
  cvt_kernel<<<NC*NC/4/256, 256, 0, stream>>>(Wp, wpj,            NC*NC/4);

  gemm_bt<0><<<dim3(3*NC/128, NM/128), 256, 0, stream>>>(xb, wqkv, NC, 3*NC,
                                                         qb, kb, vtb, nullptr);
  attn_kernel<<<dim3(NT/64, NB*NH), 256, 0, stream>>>(qb, kb, vtb, yb);
  gemm_bt<1><<<dim3(NC/128, NM/128), 256, 0, stream>>>(yb, wpj, NC, NC,
                                                       nullptr, nullptr, nullptr,
                                                       (float*)d_out);
}